// Round 8
// baseline (2564.042 us; speedup 1.0000x reference)
//
#include <hip/hip_runtime.h>
#include <hip/hip_cooperative_groups.h>
#include <math.h>

namespace cg = cooperative_groups;

#define N_VAR 8192
#define N_CHK 4096
#define DV 3
#define N_EDGE (N_VAR * DV)
#define BATCH 128
#define HB (BATCH / 2)              /* 64 packed fp16-pair lanes per row */
#define T_ITERS 30
#define ELLW 24
#define CHNK 8
#define NBLK 256
#define NTHR 1024

#define LOG2E 1.44269504088896340736f
#define LN2   0.69314718055994530942f

typedef _Float16 h2 __attribute__((ext_vector_type(2)));
typedef float f2 __attribute__((ext_vector_type(2)));

// tanh(x/2), sign preserved, |t| floored at 1e-7 (matches reference clamp);
// x pre-clipped to [-15,15]
__device__ __forceinline__ float tanh_half(float x) {
    float ex = __builtin_amdgcn_exp2f(x * LOG2E);              // e^x
    float t = 1.0f - 2.0f * __builtin_amdgcn_rcpf(ex + 1.0f);
    float s = (x < 0.0f) ? -1.0f : 1.0f;
    return s * fmaxf(fabsf(t), 1e-7f);
}

// 2*atanh(clip(p)) — reference's clip(-1+eps, 1-eps) then 2 atanh
__device__ __forceinline__ float atanh2(float p) {
    const float lim = 1.0f - 1e-7f;
    p = fminf(fmaxf(p, -lim), lim);
    return (__builtin_amdgcn_logf(1.0f + p) -
            __builtin_amdgcn_logf(1.0f - p)) * LN2;
}

// ---------------- graph build (once per launch) ----------------------------

__global__ void k_ell_scatter(const int* __restrict__ edge_chk,
                              int* __restrict__ deg_arr, int* __restrict__ ell_e) {
    int e = blockIdx.x * blockDim.x + threadIdx.x;
    if (e < N_EDGE) {
        int c = edge_chk[e];
        int pos = atomicAdd(&deg_arr[c], 1);
        if (pos < ELLW) ell_e[c * ELLW + pos] = e;   // store EDGE id
    }
}

// exclusive prefix over 4096 degs -> ptr (compact slot offsets)
__global__ __launch_bounds__(1024) void k_scan(const int* __restrict__ counts,
                                               int* __restrict__ ptr) {
    __shared__ int bufA[1024];
    __shared__ int bufB[1024];
    int t = threadIdx.x;
    int c0 = counts[4 * t + 0];
    int c1 = counts[4 * t + 1];
    int c2 = counts[4 * t + 2];
    int c3 = counts[4 * t + 3];
    int s = c0 + c1 + c2 + c3;
    bufA[t] = s;
    __syncthreads();
    int* src = bufA;
    int* dst = bufB;
    for (int off = 1; off < 1024; off *= 2) {
        int v = src[t];
        if (t >= off) v += src[t - off];
        dst[t] = v;
        __syncthreads();
        int* tmp = src; src = dst; dst = tmp;
    }
    int incl = src[t];
    int excl = incl - s;
    ptr[4 * t + 0] = excl;
    ptr[4 * t + 1] = excl + c0;
    ptr[4 * t + 2] = excl + c0 + c1;
    ptr[4 * t + 3] = excl + c0 + c1 + c2;
    if (t == 1023) ptr[N_CHK] = incl;
}

// slot_e[e] = compact slot of edge e
__global__ void k_slotmap(const int* __restrict__ ell_e,
                          const int* __restrict__ deg_arr,
                          const int* __restrict__ ptr,
                          int* __restrict__ slot_e) {
    int gid = blockIdx.x * 256 + threadIdx.x;
    if (gid < N_CHK * ELLW) {
        int c = gid / ELLW;
        int j = gid - c * ELLW;
        int d = deg_arr[c]; if (d > ELLW) d = ELLW;
        if (j < d) slot_e[ell_e[gid]] = ptr[c] + j;
    }
}

// slot4[v] = slots of v's 3 edges
__global__ void k_slot4(const int* __restrict__ slot_e, int4* __restrict__ slot4) {
    int v = blockIdx.x * 256 + threadIdx.x;
    if (v < N_VAR) {
        int4 s;
        s.x = slot_e[3 * v + 0];
        s.y = slot_e[3 * v + 1];
        s.z = slot_e[3 * v + 2];
        s.w = 0;
        slot4[v] = s;
    }
}

// chk_desc[c] = (base<<5) | min(deg,ELLW)
__global__ void k_desc(const int* __restrict__ deg_arr, const int* __restrict__ ptr,
                       int* __restrict__ chk_desc) {
    int c = blockIdx.x * 256 + threadIdx.x;
    if (c < N_CHK) {
        int d = deg_arr[c]; if (d > ELLW) d = ELLW;
        chk_desc[c] = (ptr[c] << 5) | d;
    }
}

// ---------------- phase A helper (v2c state in registers) -------------------

__device__ __forceinline__ void var_step(const h2* __restrict__ c2v,
                                         h2* __restrict__ x_arr,
                                         f2* outp, int v, int bb,
                                         const int4 s4, const f2 ch,
                                         float g, float om, float (&va)[6]) {
    h2 m0 = c2v[(size_t)s4.x * HB + bb];
    h2 m1 = c2v[(size_t)s4.y * HB + bb];
    h2 m2 = c2v[(size_t)s4.z * HB + bb];
    float a0 = (float)m0.x, b0 = (float)m0.y;
    float a1 = (float)m1.x, b1 = (float)m1.y;
    float a2 = (float)m2.x, b2 = (float)m2.y;
    float p0 = ch.x + a0 + a1 + a2;
    float p1 = ch.y + b0 + b1 + b2;
    if (outp) {
        f2 o; o.x = p0; o.y = p1;
        __builtin_nontemporal_store(o, &outp[(size_t)v * HB + bb]);
    }
    float n0, n1; h2 xw;
    n0 = g * (p0 - a0) + om * va[0]; va[0] = n0;
    n1 = g * (p1 - b0) + om * va[1]; va[1] = n1;
    xw.x = (_Float16)fminf(fmaxf(n0, -15.0f), 15.0f);
    xw.y = (_Float16)fminf(fmaxf(n1, -15.0f), 15.0f);
    x_arr[(size_t)s4.x * HB + bb] = xw;
    n0 = g * (p0 - a1) + om * va[2]; va[2] = n0;
    n1 = g * (p1 - b1) + om * va[3]; va[3] = n1;
    xw.x = (_Float16)fminf(fmaxf(n0, -15.0f), 15.0f);
    xw.y = (_Float16)fminf(fmaxf(n1, -15.0f), 15.0f);
    x_arr[(size_t)s4.y * HB + bb] = xw;
    n0 = g * (p0 - a2) + om * va[4]; va[4] = n0;
    n1 = g * (p1 - b2) + om * va[5]; va[5] = n1;
    xw.x = (_Float16)fminf(fmaxf(n0, -15.0f), 15.0f);
    xw.y = (_Float16)fminf(fmaxf(n1, -15.0f), 15.0f);
    x_arr[(size_t)s4.z * HB + bb] = xw;
}

// ---------------- persistent cooperative BP ---------------------------------
// 256 blocks x 1024 thr, all co-resident. One wave = one var (phase A, x2)
// or one check (phase B) across 64 h2 batch-pairs -> wave-uniform control,
// fully coalesced 256B transactions, zero LDS, v2c in f32 registers.

__global__ __launch_bounds__(NTHR, 4) void k_coop(
        const float* __restrict__ chn,
        const float* __restrict__ gamma_logit,
        const int4* __restrict__ slot4,
        const int* __restrict__ chk_desc,
        h2* __restrict__ c2v,
        h2* __restrict__ x_arr,
        float* __restrict__ out) {
    cg::grid_group grid = cg::this_grid();
    const int tid = threadIdx.x;
    const int gid = blockIdx.x * NTHR + tid;
    const int bb = tid & 63;
    const int v0 = __builtin_amdgcn_readfirstlane(gid >> 6);   // wave-uniform
    const int v1 = v0 + (N_VAR / 2);
    const int c  = v0;                                          // check id

    const int desc  = chk_desc[c];
    const int cbase = desc >> 5;
    const int cdeg  = desc & 31;

    const int4 sa = slot4[v0];
    const int4 sb = slot4[v1];
    const f2 cha = ((const f2*)chn)[(size_t)v0 * HB + bb];
    const f2 chb = ((const f2*)chn)[(size_t)v1 * HB + bb];

    const float g = 1.0f / (1.0f + __builtin_amdgcn_exp2f(-gamma_logit[0] * LOG2E));
    const float om = 1.0f - g;

    float va[6] = {0.f, 0.f, 0.f, 0.f, 0.f, 0.f};
    float vb[6] = {0.f, 0.f, 0.f, 0.f, 0.f, 0.f};

    const size_t SLICE = (size_t)N_VAR * BATCH;

    for (int t = 0; t < T_ITERS; ++t) {
        f2* outp = (t > 0) ? (f2*)(out + (size_t)(t - 1) * SLICE) : (f2*)0;
        var_step(c2v, x_arr, outp, v0, bb, sa, cha, g, om, va);
        var_step(c2v, x_arr, outp, v1, bb, sb, chb, g, om, vb);
        grid.sync();

        // ---- phase B: one check per thread (wave-uniform deg) ----
        if (cdeg == 1) {
            // extrinsic product is exactly 1 -> reference's clipped constant
            float m = atanh2(1.0f);
            h2 w; w.x = (_Float16)m; w.y = (_Float16)m;
            c2v[(size_t)cbase * HB + bb] = w;
        } else if (cdeg > 0) {
            float t0[ELLW], t1[ELLW];
            float P0 = 1.0f, P1 = 1.0f;
#pragma unroll
            for (int j = 0; j < ELLW; ++j)
                if (j < cdeg) {
                    h2 xv = x_arr[(size_t)(cbase + j) * HB + bb];
                    float ta = tanh_half((float)xv.x);
                    float tb = tanh_half((float)xv.y);
                    t0[j] = ta; t1[j] = tb;
                    P0 *= ta; P1 *= tb;
                }
#pragma unroll
            for (int j = 0; j < ELLW; ++j)
                if (j < cdeg) {
                    // Newton-refined reciprocal: rel err ~1e-13 (exact division)
                    float ra = __builtin_amdgcn_rcpf(t0[j]);
                    ra = ra * (2.0f - t0[j] * ra);
                    float rb = __builtin_amdgcn_rcpf(t1[j]);
                    rb = rb * (2.0f - t1[j] * rb);
                    h2 w;
                    w.x = (_Float16)atanh2(P0 * ra);
                    w.y = (_Float16)atanh2(P1 * rb);
                    c2v[(size_t)(cbase + j) * HB + bb] = w;
                }
        }
        grid.sync();
    }

    // ---- final posterior slice out[T-1] ----
    {
        f2* outp = (f2*)(out + (size_t)(T_ITERS - 1) * SLICE);
        h2 m0 = c2v[(size_t)sa.x * HB + bb];
        h2 m1 = c2v[(size_t)sa.y * HB + bb];
        h2 m2 = c2v[(size_t)sa.z * HB + bb];
        f2 o;
        o.x = cha.x + (float)m0.x + (float)m1.x + (float)m2.x;
        o.y = cha.y + (float)m0.y + (float)m1.y + (float)m2.y;
        __builtin_nontemporal_store(o, &outp[(size_t)v0 * HB + bb]);
        m0 = c2v[(size_t)sb.x * HB + bb];
        m1 = c2v[(size_t)sb.y * HB + bb];
        m2 = c2v[(size_t)sb.z * HB + bb];
        o.x = chb.x + (float)m0.x + (float)m1.x + (float)m2.x;
        o.y = chb.y + (float)m0.y + (float)m1.y + (float)m2.y;
        __builtin_nontemporal_store(o, &outp[(size_t)v1 * HB + bb]);
    }
}

// ================= fallback path (round-5 validated, 60 launches) ===========

__global__ __launch_bounds__(256) void k_varF(
        const float* __restrict__ chn, const h2* __restrict__ c2v,
        h2* __restrict__ v2c, h2* __restrict__ x_arr,
        float* __restrict__ out_prev, const int have_out,
        const float* __restrict__ gamma_logit, const int4* __restrict__ slot4) {
    int gid = blockIdx.x * 256 + threadIdx.x;    // 0 .. N_VAR*HB-1
    int v = gid >> 6;
    int bb = gid & 63;
    float g = 1.0f / (1.0f + __builtin_amdgcn_exp2f(-gamma_logit[0] * LOG2E));
    float om = 1.0f - g;
    int4 s4 = slot4[v];
    int sl[3] = {s4.x, s4.y, s4.z};
    h2 c0 = c2v[(size_t)s4.x * HB + bb];
    h2 c1 = c2v[(size_t)s4.y * HB + bb];
    h2 c2 = c2v[(size_t)s4.z * HB + bb];
    f2 ch = ((const f2*)chn)[(size_t)v * HB + bb];
    float p0 = ch.x + (float)c0.x + (float)c1.x + (float)c2.x;
    float p1 = ch.y + (float)c0.y + (float)c1.y + (float)c2.y;
    if (have_out) {
        f2 o; o.x = p0; o.y = p1;
        __builtin_nontemporal_store(o, &((f2*)out_prev)[(size_t)v * HB + bb]);
    }
    float cc0[3] = {(float)c0.x, (float)c1.x, (float)c2.x};
    float cc1[3] = {(float)c0.y, (float)c1.y, (float)c2.y};
#pragma unroll
    for (int i = 0; i < 3; ++i) {
        size_t vi = (size_t)i * (N_VAR * HB) + (size_t)v * HB + bb;
        h2 vo = v2c[vi];
        float vn0 = g * (p0 - cc0[i]) + om * (float)vo.x;
        float vn1 = g * (p1 - cc1[i]) + om * (float)vo.y;
        h2 w; w.x = (_Float16)vn0; w.y = (_Float16)vn1;
        v2c[vi] = w;
        h2 xw;
        xw.x = (_Float16)fminf(fmaxf(vn0, -15.0f), 15.0f);
        xw.y = (_Float16)fminf(fmaxf(vn1, -15.0f), 15.0f);
        x_arr[(size_t)sl[i] * HB + bb] = xw;
    }
}

__global__ __launch_bounds__(256) void k_chkF(
        const h2* __restrict__ x_arr, h2* __restrict__ c2v,
        const int* __restrict__ deg_arr, const int* __restrict__ ptr) {
    int c = blockIdx.x * 4 + (threadIdx.x >> 6);
    int bb = threadIdx.x & 63;
    int deg = deg_arr[c];
    if (deg > ELLW) deg = ELLW;
    if (deg == 0) return;
    int base = ptr[c];
    f2 tv[ELLW];
#define LOAD_BATCH(J0)                                                         \
    {                                                                          \
        h2 raw[CHNK];                                                          \
        _Pragma("unroll")                                                      \
        for (int u = 0; u < CHNK; ++u) {                                       \
            int s = base + (J0) + u;                                           \
            s = (s < N_EDGE) ? s : (N_EDGE - 1);                               \
            raw[u] = x_arr[(size_t)s * HB + bb];                               \
        }                                                                      \
        _Pragma("unroll")                                                      \
        for (int u = 0; u < CHNK; ++u) {                                       \
            int j = (J0) + u;                                                  \
            if (j < deg) {                                                     \
                f2 tf;                                                         \
                tf.x = tanh_half((float)raw[u].x);                             \
                tf.y = tanh_half((float)raw[u].y);                             \
                tv[j] = tf;                                                    \
            }                                                                  \
        }                                                                      \
    }
    LOAD_BATCH(0)
    if (deg > CHNK) LOAD_BATCH(CHNK)
    if (deg > 2 * CHNK) LOAD_BATCH(2 * CHNK)
#undef LOAD_BATCH
    f2 ext[ELLW];
    f2 run; run.x = 1.0f; run.y = 1.0f;
#pragma unroll
    for (int j = ELLW - 1; j >= 0; --j) {
        if (j < deg) { ext[j] = run; run.x *= tv[j].x; run.y *= tv[j].y; }
    }
    f2 pfx; pfx.x = 1.0f; pfx.y = 1.0f;
#pragma unroll
    for (int j = 0; j < ELLW; ++j) {
        if (j < deg) {
            float p0 = pfx.x * ext[j].x;
            float p1 = pfx.y * ext[j].y;
            pfx.x *= tv[j].x; pfx.y *= tv[j].y;
            h2 w;
            w.x = (_Float16)atanh2(p0);
            w.y = (_Float16)atanh2(p1);
            c2v[(size_t)(base + j) * HB + bb] = w;
        }
    }
}

__global__ __launch_bounds__(256) void k_finalF(
        const float* __restrict__ chn, const h2* __restrict__ c2v,
        const int4* __restrict__ slot4, float* __restrict__ out_last) {
    int gid = blockIdx.x * 256 + threadIdx.x;
    int v = gid >> 6;
    int bb = gid & 63;
    int4 s4 = slot4[v];
    h2 c0 = c2v[(size_t)s4.x * HB + bb];
    h2 c1 = c2v[(size_t)s4.y * HB + bb];
    h2 c2 = c2v[(size_t)s4.z * HB + bb];
    f2 ch = ((const f2*)chn)[(size_t)v * HB + bb];
    f2 o;
    o.x = ch.x + (float)c0.x + (float)c1.x + (float)c2.x;
    o.y = ch.y + (float)c0.y + (float)c1.y + (float)c2.y;
    __builtin_nontemporal_store(o, &((f2*)out_last)[(size_t)v * HB + bb]);
}

// ---------------- Launch ---------------------------------------------------

extern "C" void kernel_launch(void* const* d_in, const int* in_sizes, int n_in,
                              void* d_out, int out_size, void* d_ws, size_t ws_size,
                              hipStream_t stream) {
    const float* chn         = (const float*)d_in[0];
    const float* gamma_logit = (const float*)d_in[1];
    const int* edge_chk      = (const int*)d_in[3];
    float* out = (float*)d_out;

    const size_t MSGH = (size_t)N_EDGE * HB;               // h2 elems per array
    h2* c2v     = (h2*)d_ws;
    h2* x_arr   = c2v + MSGH;
    h2* v2c     = x_arr + MSGH;                            // fallback only
    int4* slot4 = (int4*)(v2c + 3 * (size_t)N_VAR * HB);
    int* slot_e = (int*)(slot4 + N_VAR);
    int* ell_e  = slot_e + N_EDGE;
    int* deg_arr= ell_e + (size_t)N_CHK * ELLW;
    int* ptr    = deg_arr + N_CHK;                         // N_CHK+1 ints
    int* chk_desc = ptr + N_CHK + 1;

    (void)hipMemsetAsync(c2v, 0, MSGH * sizeof(h2), stream);
    (void)hipMemsetAsync(v2c, 0, 3 * (size_t)N_VAR * HB * sizeof(h2), stream);
    (void)hipMemsetAsync(slot_e, 0, (size_t)N_EDGE * sizeof(int), stream);
    (void)hipMemsetAsync(deg_arr, 0, N_CHK * sizeof(int), stream);

    k_ell_scatter<<<(N_EDGE + 255) / 256, 256, 0, stream>>>(edge_chk, deg_arr,
                                                            ell_e);
    k_scan<<<1, 1024, 0, stream>>>(deg_arr, ptr);
    k_slotmap<<<(N_CHK * ELLW + 255) / 256, 256, 0, stream>>>(ell_e, deg_arr,
                                                              ptr, slot_e);
    k_slot4<<<N_VAR / 256, 256, 0, stream>>>(slot_e, slot4);
    k_desc<<<N_CHK / 256, 256, 0, stream>>>(deg_arr, ptr, chk_desc);

    void* params[] = {(void*)&chn, (void*)&gamma_logit, (void*)&slot4,
                      (void*)&chk_desc, (void*)&c2v, (void*)&x_arr, (void*)&out};
    hipError_t err = hipLaunchCooperativeKernel(
        (const void*)k_coop, dim3(NBLK), dim3(NTHR), params, 0, stream);

    if (err != hipSuccess) {
        // fallback: validated round-5 structure (60 launches)
        const size_t SLICE = (size_t)N_VAR * BATCH;
        for (int t = 0; t < T_ITERS; ++t) {
            float* out_prev = (t == 0) ? out : out + (size_t)(t - 1) * SLICE;
            k_varF<<<(N_VAR * HB) / 256, 256, 0, stream>>>(
                chn, c2v, v2c, x_arr, out_prev, (t > 0) ? 1 : 0, gamma_logit,
                slot4);
            k_chkF<<<N_CHK / 4, 256, 0, stream>>>(x_arr, c2v, deg_arr, ptr);
        }
        k_finalF<<<(N_VAR * HB) / 256, 256, 0, stream>>>(
            chn, c2v, slot4, out + (size_t)(T_ITERS - 1) * SLICE);
    }
}

// Round 9
// 575.114 us; speedup vs baseline: 4.4583x; 4.4583x over previous
//
#include <hip/hip_runtime.h>
#include <math.h>

#define N_VAR 8192
#define N_CHK 4096
#define DV 3
#define N_EDGE (N_VAR * DV)
#define BATCH 128
#define T_ITERS 30
#define ELLW 24
#define SLOT_MAX (N_EDGE + 3 * N_CHK)   /* 36864: sum of padded degs bound */

#define LOG2E 1.44269504088896340736f
#define LN2   0.69314718055994530942f

typedef _Float16 h4 __attribute__((ext_vector_type(4)));

// tanh(x/2), sign preserved, |t| floored at 1e-7 (matches reference clamp);
// x pre-clipped to [-15,15]
__device__ __forceinline__ float tanh_half(float x) {
    float ex = __builtin_amdgcn_exp2f(x * LOG2E);              // e^x
    float t = 1.0f - 2.0f * __builtin_amdgcn_rcpf(ex + 1.0f);
    float s = (x < 0.0f) ? -1.0f : 1.0f;
    return s * fmaxf(fabsf(t), 1e-7f);
}

// 2*atanh(clip(p)) — reference's clip(-1+eps, 1-eps) then 2 atanh
__device__ __forceinline__ float atanh2(float p) {
    const float lim = 1.0f - 1e-7f;
    p = fminf(fmaxf(p, -lim), lim);
    return (__builtin_amdgcn_logf(1.0f + p) -
            __builtin_amdgcn_logf(1.0f - p)) * LN2;
}

// Newton-refined reciprocal (validated R8 k_coop, absmax 0.125)
__device__ __forceinline__ float rcp_nr(float x) {
    float r = __builtin_amdgcn_rcpf(x);
    return r * (2.0f - x * r);
}

// ---------------- graph build (once per launch) ----------------------------

__global__ void k_ell_scatter(const int* __restrict__ edge_chk,
                              int* __restrict__ deg_arr, int* __restrict__ ell_e) {
    int e = blockIdx.x * blockDim.x + threadIdx.x;
    if (e < N_EDGE) {
        int c = edge_chk[e];
        int pos = atomicAdd(&deg_arr[c], 1);
        if (pos < ELLW) ell_e[c * ELLW + pos] = e;   // store EDGE id
    }
}

__global__ void k_hist(const int* __restrict__ deg_arr, int* __restrict__ hist) {
    int c = blockIdx.x * 256 + threadIdx.x;
    if (c < N_CHK) {
        int d = deg_arr[c]; if (d > ELLW) d = ELLW;
        atomicAdd(&hist[d], 1);
    }
}

// serial prefix over 25 degree buckets: check-index base + padded-slot base
__global__ void k_buckets(const int* __restrict__ hist,
                          int* __restrict__ bucket_base,
                          int* __restrict__ slot_off) {
    if (threadIdx.x == 0 && blockIdx.x == 0) {
        int cb = 0, sb = 0;
        for (int d = 0; d <= ELLW; ++d) {
            bucket_base[d] = cb;
            slot_off[d] = sb;
            int pd = (d == 0) ? 0 : ((d + 3) & ~3);
            cb += hist[d];
            sb += hist[d] * pd;
        }
    }
}

// place each check into its degree bucket: sorted desc + per-check base
__global__ void k_place(const int* __restrict__ deg_arr, int* __restrict__ cursor,
                        const int* __restrict__ bucket_base,
                        const int* __restrict__ slot_off,
                        int* __restrict__ s_desc_g, int* __restrict__ chk_base) {
    int c = blockIdx.x * 256 + threadIdx.x;
    if (c < N_CHK) {
        int d = deg_arr[c]; if (d > ELLW) d = ELLW;
        int pd = (d + 3) & ~3;
        int pos = atomicAdd(&cursor[d], 1);
        int i = bucket_base[d] + pos;
        int base = slot_off[d] + pos * pd;
        s_desc_g[i] = (base << 5) | d;
        chk_base[c] = base;
    }
}

// slot_e[e] = padded compact slot of edge e
__global__ void k_slotmap2(const int* __restrict__ ell_e,
                           const int* __restrict__ deg_arr,
                           const int* __restrict__ chk_base,
                           int* __restrict__ slot_e) {
    int gid = blockIdx.x * 256 + threadIdx.x;
    if (gid < N_CHK * ELLW) {
        int c = gid / ELLW;
        int j = gid - c * ELLW;
        int d = deg_arr[c]; if (d > ELLW) d = ELLW;
        if (j < d) slot_e[ell_e[gid]] = chk_base[c] + j;
    }
}

// slot4[v] = slots of v's 3 edges
__global__ void k_slot4(const int* __restrict__ slot_e, int4* __restrict__ slot4) {
    int v = blockIdx.x * 256 + threadIdx.x;
    if (v < N_VAR) {
        int4 s;
        s.x = slot_e[3 * v + 0];
        s.y = slot_e[3 * v + 1];
        s.z = slot_e[3 * v + 2];
        s.w = 0;
        slot4[v] = s;
    }
}

// ---------------- persistent per-batch-element BP (v2) ----------------------
// One block per batch element. Single in-place LDS msg array (72 KB):
// phase A reads c2v from msg[slot], writes x to the same slot (owner-exclusive);
// phase B reads x via b64 (bases 8B-aligned by padding), writes c2v back b64.
// Checks processed in degree-sorted order -> wave-uniform deg, no divergence.
// v2c in f32 registers; slot4/chn/desc cached in registers.

__global__ __launch_bounds__(1024) void k_bp2(
        const float* __restrict__ chn,
        const float* __restrict__ gamma_logit,
        const int4* __restrict__ slot4,
        const int* __restrict__ s_desc_g,
        float* __restrict__ outT) {         // (T, BATCH, N_VAR)
    __shared__ __align__(16) _Float16 msg[SLOT_MAX];
    const int b = blockIdx.x;
    const int tid = threadIdx.x;

    for (int i = tid; i < SLOT_MAX; i += 1024) msg[i] = (_Float16)0.0f;

    const float g = 1.0f / (1.0f + __builtin_amdgcn_exp2f(-gamma_logit[0] * LOG2E));
    const float om = 1.0f - g;
    const float AT1 = atanh2(1.0f);         // deg-1 extrinsic constant

    float chn_r[8];
    float v2c_r[8][3];
    int4 s4r[8];
    int desc_r[4];
#pragma unroll
    for (int k = 0; k < 8; ++k) {
        int v = tid + k * 1024;
        chn_r[k] = chn[(size_t)v * BATCH + b];
        s4r[k] = slot4[v];
        v2c_r[k][0] = 0.0f; v2c_r[k][1] = 0.0f; v2c_r[k][2] = 0.0f;
    }
#pragma unroll
    for (int m = 0; m < 4; ++m) desc_r[m] = s_desc_g[m * 1024 + tid];
    __syncthreads();

    const size_t SLICE = (size_t)N_VAR * BATCH;

    for (int t = 0; t < T_ITERS; ++t) {
        // ---- phase A: variables (8 per thread), in-place c2v -> x ----
#pragma unroll
        for (int k = 0; k < 8; ++k) {
            int v = tid + k * 1024;
            int4 s4 = s4r[k];
            float c0 = (float)msg[s4.x];
            float c1 = (float)msg[s4.y];
            float c2 = (float)msg[s4.z];
            float post = chn_r[k] + c0 + c1 + c2;
            if (t > 0) {
                __builtin_nontemporal_store(post,
                    &outT[(size_t)(t - 1) * SLICE + (size_t)b * N_VAR + v]);
            }
            float vn0 = g * (post - c0) + om * v2c_r[k][0];
            float vn1 = g * (post - c1) + om * v2c_r[k][1];
            float vn2 = g * (post - c2) + om * v2c_r[k][2];
            v2c_r[k][0] = vn0; v2c_r[k][1] = vn1; v2c_r[k][2] = vn2;
            msg[s4.x] = (_Float16)fminf(fmaxf(vn0, -15.0f), 15.0f);
            msg[s4.y] = (_Float16)fminf(fmaxf(vn1, -15.0f), 15.0f);
            msg[s4.z] = (_Float16)fminf(fmaxf(vn2, -15.0f), 15.0f);
        }
        __syncthreads();

        // ---- phase B: checks (4 per thread, degree-sorted) ----
#pragma unroll
        for (int m = 0; m < 4; ++m) {
            int desc = desc_r[m];
            int base = desc >> 5;
            int deg = desc & 31;
            if (deg == 1) {
                msg[base] = (_Float16)AT1;
            } else if (deg > 1) {
                int nw = (deg + 3) >> 2;
                h4 raw[6];
#pragma unroll
                for (int w = 0; w < 6; ++w)
                    if (w < nw) raw[w] = *(const h4*)&msg[base + 4 * w];
                float tv[ELLW];
                float P = 1.0f;
#pragma unroll
                for (int j = 0; j < ELLW; ++j)
                    if (j < deg) {
                        tv[j] = tanh_half((float)raw[j >> 2][j & 3]);
                        P *= tv[j];
                    }
#pragma unroll
                for (int w = 0; w < 6; ++w)
                    if (w < nw) {
                        h4 out_w;
#pragma unroll
                        for (int q = 0; q < 4; ++q) {
                            int j = 4 * w + q;
                            float m2 = (j < deg) ? atanh2(P * rcp_nr(tv[j])) : 0.0f;
                            out_w[q] = (_Float16)m2;
                        }
                        *(h4*)&msg[base + 4 * w] = out_w;
                    }
            }
        }
        __syncthreads();
    }

    // ---- final posterior row (after last check update) ----
#pragma unroll
    for (int k = 0; k < 8; ++k) {
        int v = tid + k * 1024;
        int4 s4 = s4r[k];
        float post = chn_r[k] + (float)msg[s4.x] + (float)msg[s4.y] +
                     (float)msg[s4.z];
        __builtin_nontemporal_store(post,
            &outT[(size_t)(T_ITERS - 1) * SLICE + (size_t)b * N_VAR + v]);
    }
}

// ---------------- transpose (T,B,V) -> (T,V,B) (validated R7) ---------------

__global__ __launch_bounds__(256) void k_transpose(const float* __restrict__ src,
                                                   float* __restrict__ dst) {
    __shared__ float tile[32][33];
    int t = blockIdx.z;
    int v0 = blockIdx.x * 32;
    int b0 = blockIdx.y * 32;
    int lx = threadIdx.x;            // 32 wide
    int ly = threadIdx.y;            // 8
    const float* s = src + (size_t)t * N_VAR * BATCH;
    float* d = dst + (size_t)t * N_VAR * BATCH;
#pragma unroll
    for (int i = 0; i < 32; i += 8)
        tile[ly + i][lx] = s[(size_t)(b0 + ly + i) * N_VAR + v0 + lx];
    __syncthreads();
#pragma unroll
    for (int i = 0; i < 32; i += 8)
        __builtin_nontemporal_store(tile[lx][ly + i],
            &d[(size_t)(v0 + ly + i) * BATCH + b0 + lx]);
}

// ---------------- Launch ---------------------------------------------------

extern "C" void kernel_launch(void* const* d_in, const int* in_sizes, int n_in,
                              void* d_out, int out_size, void* d_ws, size_t ws_size,
                              hipStream_t stream) {
    const float* chn         = (const float*)d_in[0];
    const float* gamma_logit = (const float*)d_in[1];
    // d_in[2] = edge_var (deterministic: e/3) — not needed
    const int* edge_chk      = (const int*)d_in[3];
    float* out = (float*)d_out;

    // workspace layout: tables first, then transposed-out scratch
    int4* slot4      = (int4*)d_ws;                        // N_VAR
    int* slot_e      = (int*)(slot4 + N_VAR);              // N_EDGE
    int* ell_e       = slot_e + N_EDGE;                    // N_CHK*ELLW
    int* deg_arr     = ell_e + (size_t)N_CHK * ELLW;       // N_CHK
    int* chk_base    = deg_arr + N_CHK;                    // N_CHK
    int* s_desc_g    = chk_base + N_CHK;                   // N_CHK
    int* hist        = s_desc_g + N_CHK;                   // 32
    int* cursor      = hist + 32;                          // 32
    int* bucket_base = cursor + 32;                        // 32
    int* slot_off    = bucket_base + 32;                   // 32
    size_t table_bytes = (char*)(slot_off + 32) - (char*)d_ws;
    size_t outT_off = (table_bytes + 255) & ~(size_t)255;
    float* outT = (float*)((char*)d_ws + outT_off);

    (void)hipMemsetAsync(slot_e, 0, (size_t)N_EDGE * sizeof(int), stream);
    (void)hipMemsetAsync(deg_arr, 0, N_CHK * sizeof(int), stream);
    (void)hipMemsetAsync(hist, 0, 64 * sizeof(int), stream);   // hist + cursor

    k_ell_scatter<<<(N_EDGE + 255) / 256, 256, 0, stream>>>(edge_chk, deg_arr,
                                                            ell_e);
    k_hist<<<N_CHK / 256, 256, 0, stream>>>(deg_arr, hist);
    k_buckets<<<1, 64, 0, stream>>>(hist, bucket_base, slot_off);
    k_place<<<N_CHK / 256, 256, 0, stream>>>(deg_arr, cursor, bucket_base,
                                             slot_off, s_desc_g, chk_base);
    k_slotmap2<<<(N_CHK * ELLW + 255) / 256, 256, 0, stream>>>(ell_e, deg_arr,
                                                               chk_base, slot_e);
    k_slot4<<<N_VAR / 256, 256, 0, stream>>>(slot_e, slot4);

    k_bp2<<<BATCH, 1024, 0, stream>>>(chn, gamma_logit, slot4, s_desc_g, outT);

    dim3 tg(N_VAR / 32, BATCH / 32, T_ITERS);
    dim3 tb(32, 8, 1);
    k_transpose<<<tg, tb, 0, stream>>>(outT, out);
}